// Round 10
// baseline (112.660 us; speedup 1.0000x reference)
//
#include <hip/hip_runtime.h>

// B=4, IN_C=64, IN_S=16384, OUT_C=64, OUT_S=4096, K=4.
// out[b,o,s] = bias[o,s] + sum_{i,k} x[b,i,4s+k] * w[i,k,o,s]
//
// R10: w-load contiguity test at constant occupancy/instr-rate.
//   thread = 4 consecutive s x 1 o x 2 b -> 8 outputs (same as R1)
//   block  = 256 threads = 512 s x 2 o x 2 b
//   grid   = 8 s-tiles x 32 o-groups x 2 b-halves = 512 blocks (8 waves/CU)
// vs R1/R9 (63 us): ONLY the load shapes change:
//   w: 4 x dwordx4 per iter, each instruction = 1 KB contiguous per wave
//      (R1: 8 x dword = 256 B granules). Each w element still read once.
//   x: per b, 4 float4 at 64 B lane-stride (4 instr share the same 64 B line
//      per lane; lines fetched once, full bytes used).
// XCD swizzle: 64 consecutive wgids per XCD = one s-tile x all (og,bh) ->
// per-XCD x slice 2 MB L2-resident.

__global__ __launch_bounds__(256) void adj1d_kernel(
    const float* __restrict__ x, const float* __restrict__ w,
    const float* __restrict__ bias, float* __restrict__ out) {

  int bid = blockIdx.x;                  // 0..511
  int wgid = (bid & 7) * 64 + (bid >> 3);
  int st = wgid >> 6;                    // s-tile (512 s)
  int rem = wgid & 63;
  int og = rem >> 1;                     // o-group (2 o)
  int bh = rem & 1;                      // b-half
  int t = threadIdx.x;
  int o_sub = t >> 7;                    // 0..1
  int s_idx = t & 127;                   // 0..127
  int s0 = (st << 9) + (s_idx << 2);     // first of this thread's 4 s
  int o  = (og << 1) + o_sub;
  int b0 = bh << 1;                      // first of this thread's 2 b

  // acc[j][bb]: j = s offset 0..3, bb = b offset 0..1
  float acc[4][2];
  #pragma unroll
  for (int j = 0; j < 4; ++j) { acc[j][0] = 0.f; acc[j][1] = 0.f; }

  const float4* __restrict__ xv = reinterpret_cast<const float4*>(x);
  const float4* __restrict__ wv4 = reinterpret_cast<const float4*>(w);
  // x float4 idx for (b,i), j-th quad: ((b*64+i)<<12) + s0 + j   (j=0..3)
  // w float4 idx for (i,k): ((i*4+k)*64 + o)*1024 + (s0>>2)
  int s0q = (st << 7) + s_idx;           // s0 >> 2
  int wbase = (o << 10) + s0q;           // + (i*4+k)*65536

  #pragma unroll 2
  for (int i = 0; i < 64; ++i) {
    // x: 2 b x 4 float4 = 16 consecutive floats per b
    float xb[2][16];
    #pragma unroll
    for (int bb = 0; bb < 2; ++bb) {
      int xbase = (((b0 + bb) << 6) + i) << 12;
      #pragma unroll
      for (int j = 0; j < 4; ++j)
        *reinterpret_cast<float4*>(&xb[bb][4 * j]) = xv[xbase + s0 + j];
    }
    // w: 4 dwordx4 loads, each 1 KB contiguous per wave
    float4 wq[4];
    #pragma unroll
    for (int k = 0; k < 4; ++k)
      wq[k] = wv4[((i * 4 + k) << 16) + wbase];

    #pragma unroll
    for (int k = 0; k < 4; ++k) {
      const float wk[4] = {wq[k].x, wq[k].y, wq[k].z, wq[k].w};
      #pragma unroll
      for (int j = 0; j < 4; ++j) {
        acc[j][0] = fmaf(xb[0][4 * j + k], wk[j], acc[j][0]);
        acc[j][1] = fmaf(xb[1][4 * j + k], wk[j], acc[j][1]);
      }
    }
  }

  float4 bv = reinterpret_cast<const float4*>(bias)[(o << 10) + s0q];
  const float bj[4] = {bv.x, bv.y, bv.z, bv.w};
  #pragma unroll
  for (int bb = 0; bb < 2; ++bb) {
    float4 r;
    r.x = acc[0][bb] + bj[0];
    r.y = acc[1][bb] + bj[1];
    r.z = acc[2][bb] + bj[2];
    r.w = acc[3][bb] + bj[3];
    reinterpret_cast<float4*>(out)[((((b0 + bb) << 6) + o) << 10) + s0q] = r;
  }
}

extern "C" void kernel_launch(void* const* d_in, const int* in_sizes, int n_in,
                              void* d_out, int out_size, void* d_ws, size_t ws_size,
                              hipStream_t stream) {
  const float* x    = (const float*)d_in[0];  // (4, 64, 16384)
  const float* w    = (const float*)d_in[1];  // (64, 4, 64, 4096)
  const float* bias = (const float*)d_in[2];  // (64, 4096)
  float* out = (float*)d_out;                 // (4, 64, 4096)

  // 8 s-tiles x 32 o-groups x 2 b-halves = 512 blocks, 256 threads each
  adj1d_kernel<<<512, 256, 0, stream>>>(x, w, bias, out);
}

// Round 11
// 82.829 us; speedup vs baseline: 1.3601x; 1.3601x over previous
//
#include <hip/hip_runtime.h>

// B=4, IN_C=64, IN_S=16384, OUT_C=64, OUT_S=4096, K=4.
// out[b,o,s] = bias[o,s] + sum_{i,k} x[b,i,4s+k] * w[i,k,o,s]
//
// R11: clean 16-waves/CU occupancy test (no atomics, no i-split, no LDS).
//   thread = 1 s x 1 o x 4 b -> 4 accumulators
//   block  = 256 threads = 4 waves = 4 o x one 64-s tile
//   grid   = 64 s-tiles x 16 o-quads = 1024 blocks (4/CU, 16 waves/CU)
// Unchanged vs R1/R9 (the 63-us points):
//   - x: dense float4/lane (16B, wave reads 1KB contiguous); the block's 4
//     waves read IDENTICAL x addresses -> L1 broadcast
//   - w: dword/lane (256B/wave chunks), 4 streams/iter, read ONCE grid-wide
//   - XCD swizzle: 128 consecutive wgids/XCD = 8 s-tiles x all 16 o-quads ->
//     x slice ~2.1 MB L2-resident, sharers co-resident
// Variable under test: waves/CU 8 -> 16 (per-wave microstructure constant).

__global__ __launch_bounds__(256) void adj1d_kernel(
    const float* __restrict__ x, const float* __restrict__ w,
    const float* __restrict__ bias, float* __restrict__ out) {

  int bid = blockIdx.x;                 // 0..1023
  int wgid = (bid & 7) * 128 + (bid >> 3);
  int oq = wgid & 15;                   // o-quad group
  int st = wgid >> 4;                   // s-tile (64 s)
  int lane = threadIdx.x & 63;
  int wv   = threadIdx.x >> 6;          // wave id = o within the quad
  int s = (st << 6) + lane;
  int o = (oq << 2) + wv;

  float acc0 = 0.f, acc1 = 0.f, acc2 = 0.f, acc3 = 0.f;   // b = 0..3

  const float4* __restrict__ xv = reinterpret_cast<const float4*>(x);
  // w element index: ((i*4+k)*64 + o)*4096 + s ; per-(i,k) stride = 262144
  const float* __restrict__ wp0 = w + (o << 12) + s;

  #pragma unroll 2
  for (int i = 0; i < 64; ++i) {
    // batch all 8 loads of this iteration before any FMA
    float4 xa0 = xv[((0 * 64 + i) << 12) + s];
    float4 xa1 = xv[((1 * 64 + i) << 12) + s];
    float4 xa2 = xv[((2 * 64 + i) << 12) + s];
    float4 xa3 = xv[((3 * 64 + i) << 12) + s];
    const float* wp = wp0 + (size_t)i * 1048576;
    float w0 = wp[0];
    float w1 = wp[262144];
    float w2 = wp[524288];
    float w3 = wp[786432];

    acc0 = fmaf(xa0.x, w0, acc0); acc1 = fmaf(xa1.x, w0, acc1);
    acc2 = fmaf(xa2.x, w0, acc2); acc3 = fmaf(xa3.x, w0, acc3);
    acc0 = fmaf(xa0.y, w1, acc0); acc1 = fmaf(xa1.y, w1, acc1);
    acc2 = fmaf(xa2.y, w1, acc2); acc3 = fmaf(xa3.y, w1, acc3);
    acc0 = fmaf(xa0.z, w2, acc0); acc1 = fmaf(xa1.z, w2, acc1);
    acc2 = fmaf(xa2.z, w2, acc2); acc3 = fmaf(xa3.z, w2, acc3);
    acc0 = fmaf(xa0.w, w3, acc0); acc1 = fmaf(xa1.w, w3, acc1);
    acc2 = fmaf(xa2.w, w3, acc2); acc3 = fmaf(xa3.w, w3, acc3);
  }

  float bv = bias[(o << 12) + s];
  out[((0 * 64 + o) << 12) + s] = acc0 + bv;
  out[((1 * 64 + o) << 12) + s] = acc1 + bv;
  out[((2 * 64 + o) << 12) + s] = acc2 + bv;
  out[((3 * 64 + o) << 12) + s] = acc3 + bv;
}

extern "C" void kernel_launch(void* const* d_in, const int* in_sizes, int n_in,
                              void* d_out, int out_size, void* d_ws, size_t ws_size,
                              hipStream_t stream) {
  const float* x    = (const float*)d_in[0];  // (4, 64, 16384)
  const float* w    = (const float*)d_in[1];  // (64, 4, 64, 4096)
  const float* bias = (const float*)d_in[2];  // (64, 4096)
  float* out = (float*)d_out;                 // (4, 64, 4096)

  // 64 s-tiles x 16 o-quads = 1024 blocks, 256 threads each
  adj1d_kernel<<<1024, 256, 0, stream>>>(x, w, bias, out);
}

// Round 12
// 72.589 us; speedup vs baseline: 1.5520x; 1.1411x over previous
//
#include <hip/hip_runtime.h>

// B=4, IN_C=64, IN_S=16384, OUT_C=64, OUT_S=4096, K=4.
// out[b,o,s] = bias[o,s] + sum_{i,k} x[b,i,4s+k] * w[i,k,o,s]
//
// R12: DRAM-row-locality test. R1/R9's exact per-thread/per-wave
// microstructure (thread = 1 s x 2 o x 4 b; wave = 64 s x one o-pair:
// 8 w-streams of 256 B/iter, dense float4 x loads). ONLY aggregation moves:
//   block = 512 threads = 8 waves covering 512 CONSECUTIVE s, ONE o-pair
//   -> each (i,k,o) 2 KB DRAM row is read in full by one block's 8
//      co-launched waves (R1 split each row across 2 blocks on different
//      XCDs at different times).
//   grid = 8 s-tiles x 32 o-pairs = 256 blocks (1/CU, 8 waves/CU — same
//   waves/CU as R1).
// XCD swizzle: 32 consecutive wgids per XCD = one 512-s tile x all 32
// o-pairs -> x slice 2 MB L2-resident, all readers co-resident.

__global__ __launch_bounds__(512) void adj1d_kernel(
    const float* __restrict__ x, const float* __restrict__ w,
    const float* __restrict__ bias, float* __restrict__ out) {

  int bid = blockIdx.x;                 // 0..255
  int wgid = (bid & 7) * 32 + (bid >> 3);
  int og = wgid & 31;                   // o-pair
  int st = wgid >> 5;                   // s-tile (512 s)
  int s  = (st << 9) + threadIdx.x;     // this thread's s
  int o0 = og << 1;

  float acc00 = 0.f, acc01 = 0.f, acc02 = 0.f, acc03 = 0.f;  // o0,   b=0..3
  float acc10 = 0.f, acc11 = 0.f, acc12 = 0.f, acc13 = 0.f;  // o0+1, b=0..3

  const float4* __restrict__ xv = reinterpret_cast<const float4*>(x);
  // w element index: ((i*4+k)*64 + o)*4096 + s ; per-(i,k) stride = 262144
  const float* __restrict__ wp0 = w + (o0 << 12) + s;

  #pragma unroll 2
  for (int i = 0; i < 64; ++i) {
    float xa[4][4];  // [b][k]
    *reinterpret_cast<float4*>(xa[0]) = xv[((0 * 64 + i) << 12) + s];
    *reinterpret_cast<float4*>(xa[1]) = xv[((1 * 64 + i) << 12) + s];
    *reinterpret_cast<float4*>(xa[2]) = xv[((2 * 64 + i) << 12) + s];
    *reinterpret_cast<float4*>(xa[3]) = xv[((3 * 64 + i) << 12) + s];
    #pragma unroll
    for (int k = 0; k < 4; ++k) {
      const float* wp = wp0 + (size_t)(i * 4 + k) * 262144;
      float wa = wp[0];
      float wb = wp[4096];
      acc00 = fmaf(xa[0][k], wa, acc00);
      acc01 = fmaf(xa[1][k], wa, acc01);
      acc02 = fmaf(xa[2][k], wa, acc02);
      acc03 = fmaf(xa[3][k], wa, acc03);
      acc10 = fmaf(xa[0][k], wb, acc10);
      acc11 = fmaf(xa[1][k], wb, acc11);
      acc12 = fmaf(xa[2][k], wb, acc12);
      acc13 = fmaf(xa[3][k], wb, acc13);
    }
  }

  float bA = bias[(o0 << 12) + s];
  float bB = bias[((o0 + 1) << 12) + s];

  out[((0 * 64 + o0) << 12) + s]     = acc00 + bA;
  out[((1 * 64 + o0) << 12) + s]     = acc01 + bA;
  out[((2 * 64 + o0) << 12) + s]     = acc02 + bA;
  out[((3 * 64 + o0) << 12) + s]     = acc03 + bA;
  out[((0 * 64 + o0 + 1) << 12) + s] = acc10 + bB;
  out[((1 * 64 + o0 + 1) << 12) + s] = acc11 + bB;
  out[((2 * 64 + o0 + 1) << 12) + s] = acc12 + bB;
  out[((3 * 64 + o0 + 1) << 12) + s] = acc13 + bB;
}

extern "C" void kernel_launch(void* const* d_in, const int* in_sizes, int n_in,
                              void* d_out, int out_size, void* d_ws, size_t ws_size,
                              hipStream_t stream) {
  const float* x    = (const float*)d_in[0];  // (4, 64, 16384)
  const float* w    = (const float*)d_in[1];  // (64, 4, 64, 4096)
  const float* bias = (const float*)d_in[2];  // (64, 4096)
  float* out = (float*)d_out;                 // (4, 64, 4096)

  // 8 s-tiles x 32 o-pairs = 256 blocks, 512 threads each
  adj1d_kernel<<<256, 512, 0, stream>>>(x, w, bias, out);
}